// Round 1
// baseline (203.369 us; speedup 1.0000x reference)
//
#include <hip/hip_runtime.h>

#define NEG_INF_E (-1e9f)

// ---------- helpers ----------
__device__ __forceinline__ float wave_sum(float v) {
#pragma unroll
    for (int off = 32; off > 0; off >>= 1)
        v += __shfl_xor(v, off, 64);
    return v;
}

// ---------- kernel 0: q[b,k] = sum_q query[b,q] * W_q[k,q] ----------
// one wave per output element; writes q into d_out[0 .. 32768) (context region, temp)
__global__ void k_linear(const float* __restrict__ query,
                         const float* __restrict__ Wq,
                         float* __restrict__ q_out) {
    const int lane = threadIdx.x & 63;
    const int wid  = blockIdx.x * 4 + (threadIdx.x >> 6);  // 0..32767
    const int b = wid >> 10;
    const int k = wid & 1023;
    const float4* qr = (const float4*)(query + (size_t)b * 1024);
    const float4* wr = (const float4*)(Wq + (size_t)k * 1024);
    float acc = 0.f;
#pragma unroll
    for (int it = 0; it < 4; ++it) {
        float4 a = qr[lane + it * 64];
        float4 w = wr[lane + it * 64];
        acc += a.x * w.x + a.y * w.y + a.z * w.z + a.w * w.w;
    }
    acc = wave_sum(acc);
    if (lane == 0) q_out[(size_t)b * 1024 + k] = acc;
}

// ---------- kernel 1: energies[b,s] = dot(keys[b,s,:], q[b,:]) with mask ----------
// one wave per (b,s) row; keys read float4-coalesced (1 KiB per wave per instr)
__global__ void k_energy(const float* __restrict__ keys,
                         const float* __restrict__ q,
                         const int* __restrict__ mask,
                         float* __restrict__ energies) {
    const int lane = threadIdx.x & 63;
    const int wid  = blockIdx.x * 4 + (threadIdx.x >> 6);  // 0..131071 == b*4096+s
    const int b = wid >> 12;
    const float4* kr = (const float4*)(keys + (size_t)wid * 1024);
    const float4* qr = (const float4*)(q + (size_t)b * 1024);
    float acc = 0.f;
#pragma unroll
    for (int it = 0; it < 4; ++it) {
        float4 kv = kr[lane + it * 64];
        float4 qv = qr[lane + it * 64];
        acc += kv.x * qv.x + kv.y * qv.y + kv.z * qv.z + kv.w * qv.w;
    }
    acc = wave_sum(acc);
    if (lane == 0)
        energies[wid] = (mask[wid] == 0) ? NEG_INF_E : acc;
}

// ---------- kernel 2: in-place softmax over S per b; also zero the context region ----------
// grid = 32 blocks (one per b), block = 1024 threads, 4 elements/thread
__global__ void k_softmax(float* __restrict__ d_out) {
    __shared__ float red[16];
    const int b = blockIdx.x;
    const int tid = threadIdx.x;
    const int lane = tid & 63;
    const int wv = tid >> 6;  // 16 waves

    // zero context region (q is already consumed by k_energy)
    d_out[(size_t)b * 1024 + tid] = 0.f;

    float* e = d_out + 32768 + (size_t)b * 4096;
    float v[4];
    float m = -INFINITY;
#pragma unroll
    for (int i = 0; i < 4; ++i) {
        v[i] = e[tid + i * 1024];
        m = fmaxf(m, v[i]);
    }
#pragma unroll
    for (int off = 32; off > 0; off >>= 1)
        m = fmaxf(m, __shfl_xor(m, off, 64));
    if (lane == 0) red[wv] = m;
    __syncthreads();
    float bm = red[0];
#pragma unroll
    for (int i = 1; i < 16; ++i) bm = fmaxf(bm, red[i]);
    __syncthreads();  // everyone done reading red before reuse

    float s = 0.f;
#pragma unroll
    for (int i = 0; i < 4; ++i) {
        v[i] = expf(v[i] - bm);
        s += v[i];
    }
    s = wave_sum(s);
    if (lane == 0) red[wv] = s;
    __syncthreads();
    float bs = 0.f;
#pragma unroll
    for (int i = 0; i < 16; ++i) bs += red[i];
    const float inv = 1.f / bs;
#pragma unroll
    for (int i = 0; i < 4; ++i) e[tid + i * 1024] = v[i] * inv;
}

// ---------- kernel 3: context[b,:] += sum_{s in chunk} attn[b,s] * values[b,s,:] ----------
// grid = (32 b, 32 chunks of 128 rows), block = 256 threads, each owns one float4 column
__global__ void k_context(const float* __restrict__ values,
                          const float* __restrict__ attn,
                          float* __restrict__ context) {
    __shared__ float a_s[128];
    const int b = blockIdx.x;
    const int s0 = blockIdx.y * 128;
    const int tid = threadIdx.x;

    if (tid < 128) a_s[tid] = attn[(size_t)b * 4096 + s0 + tid];
    __syncthreads();

    const float4* vr = (const float4*)(values + ((size_t)b * 4096 + s0) * 1024);
    float4 acc = make_float4(0.f, 0.f, 0.f, 0.f);
#pragma unroll 4
    for (int s = 0; s < 128; ++s) {
        const float a = a_s[s];
        const float4 v = vr[(size_t)s * 256 + tid];
        acc.x += a * v.x;
        acc.y += a * v.y;
        acc.z += a * v.z;
        acc.w += a * v.w;
    }
    float* c = context + (size_t)b * 1024 + tid * 4;
    atomicAdd(c + 0, acc.x);
    atomicAdd(c + 1, acc.y);
    atomicAdd(c + 2, acc.z);
    atomicAdd(c + 3, acc.w);
}

// ---------- launch ----------
extern "C" void kernel_launch(void* const* d_in, const int* in_sizes, int n_in,
                              void* d_out, int out_size, void* d_ws, size_t ws_size,
                              hipStream_t stream) {
    const float* query  = (const float*)d_in[0];  // (32, 1024)
    const float* keys   = (const float*)d_in[1];  // (32, 4096, 1024)
    const float* values = (const float*)d_in[2];  // (32, 4096, 1024)
    const int*   mask   = (const int*)d_in[3];    // (32, 4096)
    const float* Wq     = (const float*)d_in[4];  // (1024, 1024)
    float* out = (float*)d_out;                   // [0,32768) context | [32768,163840) attn

    float* q_tmp    = out;            // context region doubles as q scratch
    float* energies = out + 32768;    // attn region holds raw energies, softmax'd in place

    k_linear<<<8192, 256, 0, stream>>>(query, Wq, q_tmp);
    k_energy<<<32768, 256, 0, stream>>>(keys, q_tmp, mask, energies);
    k_softmax<<<32, 1024, 0, stream>>>(out);
    k_context<<<dim3(32, 32), 256, 0, stream>>>(values, energies, out);
}

// Round 3
// 183.805 us; speedup vs baseline: 1.1064x; 1.1064x over previous
//
#include <hip/hip_runtime.h>

#define NEG_INF_E (-1e9f)

typedef float floatx4 __attribute__((ext_vector_type(4)));

// ---------- helpers ----------
__device__ __forceinline__ float wave_sum(float v) {
#pragma unroll
    for (int off = 32; off > 0; off >>= 1)
        v += __shfl_xor(v, off, 64);
    return v;
}

__device__ __forceinline__ floatx4 ntload4(const float* p) {
    return __builtin_nontemporal_load((const floatx4*)p);
}

// ---------- kernel 0: q[b,k] = sum_q query[b,q] * W_q[k,q] ----------
// one wave per output element; writes q into d_out[0 .. 32768) (context region, temp)
__global__ void k_linear(const float* __restrict__ query,
                         const float* __restrict__ Wq,
                         float* __restrict__ q_out) {
    const int lane = threadIdx.x & 63;
    const int wid  = blockIdx.x * 4 + (threadIdx.x >> 6);  // 0..32767
    const int b = wid >> 10;
    const int k = wid & 1023;
    const floatx4* qr = (const floatx4*)(query + (size_t)b * 1024);
    const floatx4* wr = (const floatx4*)(Wq + (size_t)k * 1024);
    float acc = 0.f;
#pragma unroll
    for (int it = 0; it < 4; ++it) {
        floatx4 a = qr[lane + it * 64];
        floatx4 w = wr[lane + it * 64];
        acc += a.x * w.x + a.y * w.y + a.z * w.z + a.w * w.w;
    }
    acc = wave_sum(acc);
    if (lane == 0) q_out[(size_t)b * 1024 + k] = acc;
}

// ---------- kernel 1: energies[b,s] = dot(keys[b,s,:], q[b,:]) with mask ----------
// one wave per (b,s) row; keys streamed nontemporally (no reuse), q from cache
__global__ void k_energy(const float* __restrict__ keys,
                         const float* __restrict__ q,
                         const int* __restrict__ mask,
                         float* __restrict__ energies) {
    const int lane = threadIdx.x & 63;
    const int wid  = blockIdx.x * 4 + (threadIdx.x >> 6);  // 0..131071 == b*4096+s
    const int b = wid >> 12;
    const float* kr = keys + (size_t)wid * 1024;
    const floatx4* qr = (const floatx4*)(q + (size_t)b * 1024);
    floatx4 kv[4], qv[4];
#pragma unroll
    for (int it = 0; it < 4; ++it) kv[it] = ntload4(kr + (lane + it * 64) * 4);
#pragma unroll
    for (int it = 0; it < 4; ++it) qv[it] = qr[lane + it * 64];
    float acc = 0.f;
#pragma unroll
    for (int it = 0; it < 4; ++it) {
        acc += kv[it].x * qv[it].x + kv[it].y * qv[it].y +
               kv[it].z * qv[it].z + kv[it].w * qv[it].w;
    }
    acc = wave_sum(acc);
    if (lane == 0)
        energies[wid] = (mask[wid] == 0) ? NEG_INF_E : acc;
}

// ---------- kernel 2: in-place softmax over S per b; also zero the context region ----------
// grid = 32 blocks (one per b), block = 1024 threads, 4 elements/thread
__global__ void k_softmax(float* __restrict__ d_out) {
    __shared__ float red[16];
    const int b = blockIdx.x;
    const int tid = threadIdx.x;
    const int lane = tid & 63;
    const int wv = tid >> 6;  // 16 waves

    // zero context region (q is already consumed by k_energy)
    d_out[(size_t)b * 1024 + tid] = 0.f;

    float* e = d_out + 32768 + (size_t)b * 4096;
    float v[4];
    float m = -INFINITY;
#pragma unroll
    for (int i = 0; i < 4; ++i) {
        v[i] = e[tid + i * 1024];
        m = fmaxf(m, v[i]);
    }
#pragma unroll
    for (int off = 32; off > 0; off >>= 1)
        m = fmaxf(m, __shfl_xor(m, off, 64));
    if (lane == 0) red[wv] = m;
    __syncthreads();
    float bm = red[0];
#pragma unroll
    for (int i = 1; i < 16; ++i) bm = fmaxf(bm, red[i]);
    __syncthreads();  // everyone done reading red before reuse

    float s = 0.f;
#pragma unroll
    for (int i = 0; i < 4; ++i) {
        v[i] = expf(v[i] - bm);
        s += v[i];
    }
    s = wave_sum(s);
    if (lane == 0) red[wv] = s;
    __syncthreads();
    float bs = 0.f;
#pragma unroll
    for (int i = 0; i < 16; ++i) bs += red[i];
    const float inv = 1.f / bs;
#pragma unroll
    for (int i = 0; i < 4; ++i) e[tid + i * 1024] = v[i] * inv;
}

// ---------- kernel 3: context[b,:] += sum_{s in chunk} attn[b,s] * values[b,s,:] ----------
// grid = (32 b, 32 chunks of 128 rows), block = 256 threads, each owns one float4 column
__global__ void k_context(const float* __restrict__ values,
                          const float* __restrict__ attn,
                          float* __restrict__ context) {
    __shared__ float a_s[128];
    const int b = blockIdx.x;
    const int s0 = blockIdx.y * 128;
    const int tid = threadIdx.x;

    if (tid < 128) a_s[tid] = attn[(size_t)b * 4096 + s0 + tid];
    __syncthreads();

    const float* vr = values + ((size_t)b * 4096 + s0) * 1024;
    floatx4 acc = (floatx4)0.f;
#pragma unroll 8
    for (int s = 0; s < 128; ++s) {
        const float a = a_s[s];
        const floatx4 v = ntload4(vr + (size_t)s * 1024 + tid * 4);
        acc.x += a * v.x;
        acc.y += a * v.y;
        acc.z += a * v.z;
        acc.w += a * v.w;
    }
    float* c = context + (size_t)b * 1024 + tid * 4;
    atomicAdd(c + 0, acc.x);
    atomicAdd(c + 1, acc.y);
    atomicAdd(c + 2, acc.z);
    atomicAdd(c + 3, acc.w);
}

// ---------- launch ----------
extern "C" void kernel_launch(void* const* d_in, const int* in_sizes, int n_in,
                              void* d_out, int out_size, void* d_ws, size_t ws_size,
                              hipStream_t stream) {
    const float* query  = (const float*)d_in[0];  // (32, 1024)
    const float* keys   = (const float*)d_in[1];  // (32, 4096, 1024)
    const float* values = (const float*)d_in[2];  // (32, 4096, 1024)
    const int*   mask   = (const int*)d_in[3];    // (32, 4096)
    const float* Wq     = (const float*)d_in[4];  // (1024, 1024)
    float* out = (float*)d_out;                   // [0,32768) context | [32768,163840) attn

    float* q_tmp    = out;            // context region doubles as q scratch
    float* energies = out + 32768;    // attn region holds raw energies, softmax'd in place

    k_linear<<<8192, 256, 0, stream>>>(query, Wq, q_tmp);
    k_energy<<<32768, 256, 0, stream>>>(keys, q_tmp, mask, energies);
    k_softmax<<<32, 1024, 0, stream>>>(out);
    k_context<<<dim3(32, 32), 256, 0, stream>>>(values, energies, out);
}

// Round 4
// 179.036 us; speedup vs baseline: 1.1359x; 1.0266x over previous
//
#include <hip/hip_runtime.h>

#define NEG_INF_E (-1e9f)

typedef float floatx4 __attribute__((ext_vector_type(4)));

// ---------- helpers ----------
__device__ __forceinline__ float wave_sum(float v) {
#pragma unroll
    for (int off = 32; off > 0; off >>= 1)
        v += __shfl_xor(v, off, 64);
    return v;
}

__device__ __forceinline__ float wave_max(float v) {
#pragma unroll
    for (int off = 32; off > 0; off >>= 1)
        v = fmaxf(v, __shfl_xor(v, off, 64));
    return v;
}

__device__ __forceinline__ floatx4 ntload4(const float* p) {
    return __builtin_nontemporal_load((const floatx4*)p);
}

// ---------- kernel 0: q[b,k] = sum_q query[b,q] * W_q[k,q] ----------
// one wave per output element. ZERO_CTX: blocks 0..127 also zero the context
// region of d_out (used by the fused path, where softmax no longer does it).
template <bool ZERO_CTX>
__global__ void k_linear(const float* __restrict__ query,
                         const float* __restrict__ Wq,
                         float* __restrict__ q_out,
                         float* __restrict__ ctx_zero) {
    const int lane = threadIdx.x & 63;
    const int wid  = blockIdx.x * 4 + (threadIdx.x >> 6);  // 0..32767
    const int b = wid >> 10;
    const int k = wid & 1023;
    if (ZERO_CTX && blockIdx.x < 128)
        ctx_zero[blockIdx.x * 256 + threadIdx.x] = 0.f;
    const floatx4* qr = (const floatx4*)(query + (size_t)b * 1024);
    const floatx4* wr = (const floatx4*)(Wq + (size_t)k * 1024);
    float acc = 0.f;
#pragma unroll
    for (int it = 0; it < 4; ++it) {
        floatx4 a = qr[lane + it * 64];
        floatx4 w = wr[lane + it * 64];
        acc += a.x * w.x + a.y * w.y + a.z * w.z + a.w * w.w;
    }
    acc = wave_sum(acc);
    if (lane == 0) q_out[(size_t)b * 1024 + k] = acc;
}

// ---------- kernel 1: energies[b,s] = dot(keys[b,s,:], q[b,:]) with mask ----------
// one wave per (b,s) row; keys streamed nontemporally (no reuse), q from cache
__global__ void k_energy(const float* __restrict__ keys,
                         const float* __restrict__ q,
                         const int* __restrict__ mask,
                         float* __restrict__ energies) {
    const int lane = threadIdx.x & 63;
    const int wid  = blockIdx.x * 4 + (threadIdx.x >> 6);  // 0..131071 == b*4096+s
    const int b = wid >> 12;
    const float* kr = keys + (size_t)wid * 1024;
    const floatx4* qr = (const floatx4*)(q + (size_t)b * 1024);
    floatx4 kv[4], qv[4];
#pragma unroll
    for (int it = 0; it < 4; ++it) kv[it] = ntload4(kr + (lane + it * 64) * 4);
#pragma unroll
    for (int it = 0; it < 4; ++it) qv[it] = qr[lane + it * 64];
    float acc = 0.f;
#pragma unroll
    for (int it = 0; it < 4; ++it) {
        acc += kv[it].x * qv[it].x + kv[it].y * qv[it].y +
               kv[it].z * qv[it].z + kv[it].w * qv[it].w;
    }
    acc = wave_sum(acc);
    if (lane == 0)
        energies[wid] = (mask[wid] == 0) ? NEG_INF_E : acc;
}

// ---------- fused kernel 2: softmax stats + attn write + context accumulate ----------
// grid = (32 b, 32 chunks of 128 rows), block = 256 threads.
// Each block redundantly computes row max / Z from the L2-resident energies row
// (deterministic: same data, same reduction order per b), normalizes and writes
// its own 128 attn values, then streams its values chunk.
__global__ void k_context_fused(const float* __restrict__ values,
                                const float* __restrict__ energies,
                                float* __restrict__ out) {  // [0,32768) ctx | [32768,...) attn
    __shared__ float red[4];
    __shared__ float a_s[128];
    const int b = blockIdx.x;
    const int s0 = blockIdx.y * 128;
    const int tid = threadIdx.x;
    const int lane = tid & 63;
    const int wv = tid >> 6;  // 4 waves

    const float* e = energies + (size_t)b * 4096;
    float ev[16];
    float m = -INFINITY;
#pragma unroll
    for (int i = 0; i < 16; ++i) {
        ev[i] = e[tid + i * 256];
        m = fmaxf(m, ev[i]);
    }
    m = wave_max(m);
    if (lane == 0) red[wv] = m;
    __syncthreads();
    const float bm = fmaxf(fmaxf(red[0], red[1]), fmaxf(red[2], red[3]));
    __syncthreads();

    float s = 0.f;
#pragma unroll
    for (int i = 0; i < 16; ++i) s += expf(ev[i] - bm);
    s = wave_sum(s);
    if (lane == 0) red[wv] = s;
    __syncthreads();
    const float inv = 1.f / (red[0] + red[1] + red[2] + red[3]);

    if (tid < 128) {
        const float a = expf(e[s0 + tid] - bm) * inv;
        a_s[tid] = a;
        __builtin_nontemporal_store(a, out + 32768 + (size_t)b * 4096 + s0 + tid);
    }
    __syncthreads();

    const float* vr = values + ((size_t)b * 4096 + s0) * 1024;
    floatx4 acc = (floatx4)0.f;
#pragma unroll 8
    for (int s2 = 0; s2 < 128; ++s2) {
        const float a = a_s[s2];
        const floatx4 v = ntload4(vr + (size_t)s2 * 1024 + tid * 4);
        acc.x += a * v.x;
        acc.y += a * v.y;
        acc.z += a * v.z;
        acc.w += a * v.w;
    }
    float* c = out + (size_t)b * 1024 + tid * 4;
    atomicAdd(c + 0, acc.x);
    atomicAdd(c + 1, acc.y);
    atomicAdd(c + 2, acc.z);
    atomicAdd(c + 3, acc.w);
}

// ---------- fallback kernels (R3 path, used only if ws_size is too small) ----------
__global__ void k_softmax(float* __restrict__ d_out) {
    __shared__ float red[16];
    const int b = blockIdx.x;
    const int tid = threadIdx.x;
    const int lane = tid & 63;
    const int wv = tid >> 6;

    d_out[(size_t)b * 1024 + tid] = 0.f;

    float* e = d_out + 32768 + (size_t)b * 4096;
    float v[4];
    float m = -INFINITY;
#pragma unroll
    for (int i = 0; i < 4; ++i) {
        v[i] = e[tid + i * 1024];
        m = fmaxf(m, v[i]);
    }
    m = wave_max(m);
    if (lane == 0) red[wv] = m;
    __syncthreads();
    float bm = red[0];
#pragma unroll
    for (int i = 1; i < 16; ++i) bm = fmaxf(bm, red[i]);
    __syncthreads();

    float s = 0.f;
#pragma unroll
    for (int i = 0; i < 4; ++i) {
        v[i] = expf(v[i] - bm);
        s += v[i];
    }
    s = wave_sum(s);
    if (lane == 0) red[wv] = s;
    __syncthreads();
    float bs = 0.f;
#pragma unroll
    for (int i = 0; i < 16; ++i) bs += red[i];
    const float inv = 1.f / bs;
#pragma unroll
    for (int i = 0; i < 4; ++i) e[tid + i * 1024] = v[i] * inv;
}

__global__ void k_context(const float* __restrict__ values,
                          const float* __restrict__ attn,
                          float* __restrict__ context) {
    __shared__ float a_s[128];
    const int b = blockIdx.x;
    const int s0 = blockIdx.y * 128;
    const int tid = threadIdx.x;

    if (tid < 128) a_s[tid] = attn[(size_t)b * 4096 + s0 + tid];
    __syncthreads();

    const float* vr = values + ((size_t)b * 4096 + s0) * 1024;
    floatx4 acc = (floatx4)0.f;
#pragma unroll 8
    for (int s = 0; s < 128; ++s) {
        const float a = a_s[s];
        const floatx4 v = ntload4(vr + (size_t)s * 1024 + tid * 4);
        acc.x += a * v.x;
        acc.y += a * v.y;
        acc.z += a * v.z;
        acc.w += a * v.w;
    }
    float* c = context + (size_t)b * 1024 + tid * 4;
    atomicAdd(c + 0, acc.x);
    atomicAdd(c + 1, acc.y);
    atomicAdd(c + 2, acc.z);
    atomicAdd(c + 3, acc.w);
}

// ---------- launch ----------
extern "C" void kernel_launch(void* const* d_in, const int* in_sizes, int n_in,
                              void* d_out, int out_size, void* d_ws, size_t ws_size,
                              hipStream_t stream) {
    const float* query  = (const float*)d_in[0];  // (32, 1024)
    const float* keys   = (const float*)d_in[1];  // (32, 4096, 1024)
    const float* values = (const float*)d_in[2];  // (32, 4096, 1024)
    const int*   mask   = (const int*)d_in[3];    // (32, 4096)
    const float* Wq     = (const float*)d_in[4];  // (1024, 1024)
    float* out = (float*)d_out;                   // [0,32768) context | [32768,163840) attn

    // need 32768 (q) + 131072 (energies) floats = 640 KB of scratch
    if (ws_size >= (32768 + 131072) * sizeof(float)) {
        float* q_tmp    = (float*)d_ws;
        float* energies = (float*)d_ws + 32768;
        k_linear<true><<<8192, 256, 0, stream>>>(query, Wq, q_tmp, out);
        k_energy<<<32768, 256, 0, stream>>>(keys, q_tmp, mask, energies);
        k_context_fused<<<dim3(32, 32), 256, 0, stream>>>(values, energies, out);
    } else {
        float* q_tmp    = out;          // context region doubles as q scratch
        float* energies = out + 32768;  // attn region holds raw energies
        k_linear<false><<<8192, 256, 0, stream>>>(query, Wq, q_tmp, out);
        k_energy<<<32768, 256, 0, stream>>>(keys, q_tmp, mask, energies);
        k_softmax<<<32, 1024, 0, stream>>>(out);
        k_context<<<dim3(32, 32), 256, 0, stream>>>(values, energies, out);
    }
}